// Round 1
// baseline (556.159 us; speedup 1.0000x reference)
//
#include <hip/hip_runtime.h>
#include <cmath>

// DarwinianRouter: fused L2-normalize + x_norm @ sig^T * 5 + top-8 + softplus.
// Outputs concatenated flat: weights[16384*8] f32, indices[16384*8] (written as
// float values), resonance[16384*64] f32.
//
// fp32 vector-FMA GEMM (no fp32 MFMA on CDNA4). Indices must match the fp32
// reference exactly (abs threshold 1.26 on integer indices), so accumulation is
// two-level blocked fp32 (~1e-8 error vs top-8 sorted gaps ~0.03).

#define N_TOKENS 16384
#define DIM      4096
#define NE       64      // experts
#define TOPK     8
#define TM       64      // tokens per block
#define BK       64      // K per tile
#define NT       (DIM / BK)
#define LSTR     68      // LDS row stride (pad 64->68: compute reads <=2-way aliased = free)
#define SCALE    5.0f
#define EPS      1e-12f

__launch_bounds__(256)
__global__ void router_kernel(const float* __restrict__ x,
                              const float* __restrict__ sig,
                              float* __restrict__ outW,
                              float* __restrict__ outI,
                              float* __restrict__ outR) {
    __shared__ float xs[TM * LSTR];
    __shared__ float ss[NE * LSTR];
    __shared__ float scales[TM];

    const int t    = threadIdx.x;
    const int tok0 = blockIdx.x * TM;

    // loader mapping: thread handles rows lr+16m (m=0..3), 16B chunk lc
    const int lr = t >> 4;
    const int lc = (t & 15) << 2;

    // compute mapping: tokens 4*ty..+3, experts tx+16j
    const int tx = t & 15;
    const int ty = t >> 4;

    const float* xg = x + (size_t)tok0 * DIM;

    float acc[4][4];
#pragma unroll
    for (int i = 0; i < 4; ++i)
#pragma unroll
        for (int j = 0; j < 4; ++j) acc[i][j] = 0.f;
    float sq[4] = {0.f, 0.f, 0.f, 0.f};

    float4 px[4], ps[4];
    // prefetch tile 0
#pragma unroll
    for (int m = 0; m < 4; ++m) {
        px[m] = *(const float4*)(xg  + (size_t)(lr + 16 * m) * DIM + lc);
        ps[m] = *(const float4*)(sig + (size_t)(lr + 16 * m) * DIM + lc);
    }

    for (int kt = 0; kt < NT; ++kt) {
        // stage prefetched tile into LDS; accumulate sum(x^2) from registers
#pragma unroll
        for (int m = 0; m < 4; ++m) {
            *(float4*)(xs + (lr + 16 * m) * LSTR + lc) = px[m];
            *(float4*)(ss + (lr + 16 * m) * LSTR + lc) = ps[m];
            sq[m] = fmaf(px[m].x, px[m].x, sq[m]);
            sq[m] = fmaf(px[m].y, px[m].y, sq[m]);
            sq[m] = fmaf(px[m].z, px[m].z, sq[m]);
            sq[m] = fmaf(px[m].w, px[m].w, sq[m]);
        }
        __syncthreads();

        // issue prefetch of next tile (overlaps with compute below)
        if (kt + 1 < NT) {
            const int k0 = (kt + 1) * BK;
#pragma unroll
            for (int m = 0; m < 4; ++m) {
                px[m] = *(const float4*)(xg  + (size_t)(lr + 16 * m) * DIM + k0 + lc);
                ps[m] = *(const float4*)(sig + (size_t)(lr + 16 * m) * DIM + k0 + lc);
            }
        }

        // compute: per-tile partial accumulators (two-level accumulation)
        float tacc[4][4];
#pragma unroll
        for (int i = 0; i < 4; ++i)
#pragma unroll
            for (int j = 0; j < 4; ++j) tacc[i][j] = 0.f;

#pragma unroll
        for (int k4 = 0; k4 < BK; k4 += 4) {
            float4 xv[4], sv[4];
#pragma unroll
            for (int i = 0; i < 4; ++i)
                xv[i] = *(const float4*)(xs + (4 * ty + i) * LSTR + k4);
#pragma unroll
            for (int j = 0; j < 4; ++j)
                sv[j] = *(const float4*)(ss + (tx + 16 * j) * LSTR + k4);
#pragma unroll
            for (int i = 0; i < 4; ++i)
#pragma unroll
                for (int j = 0; j < 4; ++j) {
                    tacc[i][j] = fmaf(xv[i].x, sv[j].x, tacc[i][j]);
                    tacc[i][j] = fmaf(xv[i].y, sv[j].y, tacc[i][j]);
                    tacc[i][j] = fmaf(xv[i].z, sv[j].z, tacc[i][j]);
                    tacc[i][j] = fmaf(xv[i].w, sv[j].w, tacc[i][j]);
                }
        }
#pragma unroll
        for (int i = 0; i < 4; ++i)
#pragma unroll
            for (int j = 0; j < 4; ++j) acc[i][j] += tacc[i][j];
        __syncthreads();
    }

    // reduce sum(x^2) across the 16 lanes sharing each loader row
#pragma unroll
    for (int m = 0; m < 4; ++m) {
        float v = sq[m];
        v += __shfl_xor(v, 1);
        v += __shfl_xor(v, 2);
        v += __shfl_xor(v, 4);
        v += __shfl_xor(v, 8);
        if ((t & 15) == 0) scales[lr + 16 * m] = v;
    }
    __syncthreads();
    if (t < TM) scales[t] = SCALE / fmaxf(sqrtf(scales[t]), EPS);
    __syncthreads();

    // epilogue: scale, write resonance to global + LDS (reuse xs, stride 65)
    float* res = xs;
#pragma unroll
    for (int i = 0; i < 4; ++i) {
        const int tok = 4 * ty + i;
        const float s = scales[tok];
#pragma unroll
        for (int j = 0; j < 4; ++j) {
            const int e = tx + 16 * j;
            const float r = acc[i][j] * s;
            outR[(size_t)(tok0 + tok) * NE + e] = r;
            res[tok * 65 + e] = r;
        }
    }
    __syncthreads();

    // top-8 per token: sequential argmax (strict '>' => lowest index on ties,
    // matching jax.lax.top_k), then softplus
    if (t < TM) {
        float* row = res + t * 65;
        const size_t ob = (size_t)(tok0 + t) * TOPK;
#pragma unroll 1
        for (int m = 0; m < TOPK; ++m) {
            float best = -__builtin_inff();
            int bi = 0;
#pragma unroll 1
            for (int e = 0; e < NE; ++e) {
                const float v = row[e];
                if (v > best) { best = v; bi = e; }
            }
            row[bi] = -__builtin_inff();
            outW[ob + m] = log1pf(expf(best));
            outI[ob + m] = (float)bi;
        }
    }
}

extern "C" void kernel_launch(void* const* d_in, const int* in_sizes, int n_in,
                              void* d_out, int out_size, void* d_ws, size_t ws_size,
                              hipStream_t stream) {
    const float* x   = (const float*)d_in[0];
    const float* sig = (const float*)d_in[1];
    float* out  = (float*)d_out;
    float* outW = out;
    float* outI = out + (size_t)N_TOKENS * TOPK;
    float* outR = out + (size_t)N_TOKENS * TOPK * 2;

    dim3 grid(N_TOKENS / TM);
    router_kernel<<<grid, 256, 0, stream>>>(x, sig, outW, outI, outR);
}